// Round 7
// baseline (1542.968 us; speedup 1.0000x reference)
//
#include <hip/hip_runtime.h>
#include <stdint.h>

#define BB     64
#define CC     12
#define LL     2048
#define KERNSZ 9
#define KK     8     // kernels per group
#define GG     32    // groups per branch (_G)
#define NPER   6
#define NDIL   8
#define WPB    4     // waves per block; 4 * 2048 * 4B = 32 KB -> 5 blocks/CU

typedef float f2 __attribute__((ext_vector_type(2)));

// VOP3P packed f32. src1 = wave-uniform SGPR *pair* (w_even, w_odd).
// Broadcast ONE half of src1 to both result halves via op_sel[1]/op_sel_hi[1];
// taps (src0) use natural lo->lo, hi->hi.
__device__ __forceinline__ void pk_fma_wlo(f2& acc, const f2& t, uint64_t wp) {
    asm("v_pk_fma_f32 %0, %1, %2, %0 op_sel:[0,0,0] op_sel_hi:[1,0,1]"
        : "+v"(acc) : "v"(t), "s"(wp));
}
__device__ __forceinline__ void pk_fma_whi(f2& acc, const f2& t, uint64_t wp) {
    asm("v_pk_fma_f32 %0, %1, %2, %0 op_sel:[0,1,0] op_sel_hi:[1,1,1]"
        : "+v"(acc) : "v"(t), "s"(wp));
}
__device__ __forceinline__ f2 pk_mul_wlo(const f2& t, uint64_t wp) {
    f2 d;
    asm("v_pk_mul_f32 %0, %1, %2 op_sel:[0,0] op_sel_hi:[1,0]"
        : "=v"(d) : "v"(t), "s"(wp));
    return d;
}

// Shared conv + max/min + equality-binning on one position pair.
// t[j] = (tap_j @ pos0, tap_j @ pos0+1). kill_hi poisons the .y position.
__device__ __forceinline__ void conv_and_bin(
    const f2 (&t)[KERNSZ], const uint64_t (&wp)[KK][4], const float (&w8)[KK],
    bool kill_hi, f2 (&accM)[KK], uint32_t (&accN)[KK])
{
    const float NANF = __uint_as_float(0x7fc00000u);

    f2 v[KK];   // v[k] = (conv_k@pos0, conv_k@pos0+1)
    #pragma unroll
    for (int k = 0; k < KK; ++k) v[k] = pk_mul_wlo(t[0], wp[k][0]);
    #pragma unroll
    for (int k = 0; k < KK; ++k) pk_fma_whi(v[k], t[1], wp[k][0]);
    #pragma unroll
    for (int m = 1; m < 4; ++m) {
        #pragma unroll
        for (int k = 0; k < KK; ++k) pk_fma_wlo(v[k], t[2 * m], wp[k][m]);
        #pragma unroll
        for (int k = 0; k < KK; ++k) pk_fma_whi(v[k], t[2 * m + 1], wp[k][m]);
    }
    #pragma unroll
    for (int k = 0; k < KK; ++k) {
        v[k].x = fmaf(w8[k], t[8].x, v[k].x);
        v[k].y = fmaf(w8[k], t[8].y, v[k].y);
    }

    float mxa = fmaxf(fmaxf(v[0].x, v[1].x), fmaxf(v[2].x, v[3].x));
    float mxb = fmaxf(fmaxf(v[4].x, v[5].x), fmaxf(v[6].x, v[7].x));
    float mx  = fmaxf(mxa, mxb);
    float mya = fmaxf(fmaxf(v[0].y, v[1].y), fmaxf(v[2].y, v[3].y));
    float myb = fmaxf(fmaxf(v[4].y, v[5].y), fmaxf(v[6].y, v[7].y));
    float my  = fmaxf(mya, myb);
    float nxa = fminf(fminf(v[0].x, v[1].x), fminf(v[2].x, v[3].x));
    float nxb = fminf(fminf(v[4].x, v[5].x), fminf(v[6].x, v[7].x));
    float nx  = fminf(nxa, nxb);
    float nya = fminf(fminf(v[0].y, v[1].y), fminf(v[2].y, v[3].y));
    float nyb = fminf(fminf(v[4].y, v[5].y), fminf(v[6].y, v[7].y));
    float ny  = fminf(nya, nyb);

    if (kill_hi) { my = NANF; ny = NANF; }   // NaN never compares equal

    #pragma unroll
    for (int k = 0; k < KK; ++k) {
        f2 am;
        am.x = (v[k].x == mx) ? v[k].x : 0.0f;   // exact: mx bit-equals winner
        am.y = (v[k].y == my) ? v[k].y : 0.0f;
        accM[k] += am;                            // v_pk_add_f32
        accN[k] += (v[k].x == nx) ? 1u : 0u;
        accN[k] += (v[k].y == ny) ? 1u : 0u;
    }
}

// Edge iteration: clamped + masked tap loads (replaces LDS pads).
__device__ __forceinline__ void edge_iter(
    const float* __restrict__ sel, int pos0, int D, unsigned Lp,
    const uint64_t (&wp)[KK][4], const float (&w8)[KK],
    f2 (&accM)[KK], uint32_t (&accN)[KK])
{
    f2 t[KERNSZ];
    #pragma unroll
    for (int j = 0; j < KERNSZ; ++j) {
        int ix = pos0 + (j - 4) * D;
        int iy = ix + 1;
        float tx = sel[min(max(ix, 0), LL - 1)];   // stay inside own buffer
        float ty = sel[min(max(iy, 0), LL - 1)];
        t[j].x = ((unsigned)ix < Lp) ? tx : 0.0f;  // zero-pad semantics
        t[j].y = ((unsigned)iy < Lp) ? ty : 0.0f;
    }
    conv_and_bin(t, wp, w8, (unsigned)(pos0 + 1) >= Lp, accM, accN);
}

// Interior: all taps provably in [0, Lp) -> unchecked LDS pair loads.
template <int D>
__device__ __forceinline__ void run_phase2(
    const float* __restrict__ sel, int lane, unsigned Lp,
    const uint64_t (&wp)[KK][4], const float (&w8)[KK],
    f2 (&accM)[KK], uint32_t (&accN)[KK])
{
    // pair-iteration q covers positions [q*128, q*128+127]
    // interior iff q*128 - 4D >= 0 and q*128 + 127 + 1 + 4D <= 2047
    constexpr int QLO = (4 * D + 127) / 128;
    constexpr int QHI = (1919 - 4 * D) / 128;

    #pragma unroll 2
    for (int q = QLO; q <= QHI; ++q) {
        const int pos0 = q * 128 + 2 * lane;
        const float* pb = sel + pos0 - 4 * D;   // 8B-aligned (all terms even)

        f2 t[KERNSZ];
        #pragma unroll
        for (int j = 0; j < KERNSZ; ++j) {
            if constexpr (D % 2 == 0) {
                t[j] = *(const f2*)(pb + j * D);   // ds_read_b64, imm offset
            } else {
                t[j].x = pb[j * D];                // ds_read2_b32
                t[j].y = pb[j * D + 1];
            }
        }
        conv_and_bin(t, wp, w8, false, accM, accN);
    }

    // edge iterations (few; D=128 worst at 9/16)
    #pragma unroll 1
    for (int q = 0; q < QLO; ++q)
        edge_iter(sel, q * 128 + 2 * lane, D, Lp, wp, w8, accM, accN);
    #pragma unroll 1
    for (int q = QHI + 1; q < 16; ++q)
        edge_iter(sel, q * 128 + 2 * lane, D, Lp, wp, w8, accM, accN);
}

__global__ __launch_bounds__(256, 5) void hydra_kernel(
    const float* __restrict__ X,    // [B, C, L]
    const float* __restrict__ W,    // [NDIL, 2, KK*GG, 1, KERNSZ]
    const int*   __restrict__ I,    // [NDIL, 2, GG, NPER]
    float*       __restrict__ out)  // [B, 8192]
{
    __shared__ float lds[WPB][LL];   // exactly 32 KB/block -> 5 blocks/CU

    const int tid  = threadIdx.x;
    const int wave = tid >> 6;
    const int lane = tid & 63;
    const int wid  = blockIdx.x * WPB + wave;   // 0..32767
    // task decode: wid = b*512 + di*64 + dif*32 + g
    const int b   = wid >> 9;
    const int r   = wid & 511;
    const int di  = r >> 6;
    const int r2  = r & 63;
    const int dif = r2 >> 5;
    const int g   = r2 & 31;
    const unsigned Lp = LL - dif;    // 2048 or 2047

    float* sel = lds[wave];

    // ---- phase 1: channel-subset sum S into sel[0..2047] (f2 loads) ----
    const int* Ig = I + ((size_t)((di * 2 + dif) * GG + g)) * NPER;
    const float* xb = X + (size_t)b * CC * LL;
    const float* c0 = xb + Ig[0] * LL;
    const float* c1 = xb + Ig[1] * LL;
    const float* c2 = xb + Ig[2] * LL;
    const float* c3 = xb + Ig[3] * LL;
    const float* c4 = xb + Ig[4] * LL;
    const float* c5 = xb + Ig[5] * LL;

    #pragma unroll 1
    for (int q = 0; q < 16; ++q) {
        int pp = (q * 64 + lane) * 2;
        f2 s = *(const f2*)(c0 + pp) + *(const f2*)(c1 + pp)
             + *(const f2*)(c2 + pp) + *(const f2*)(c3 + pp)
             + *(const f2*)(c4 + pp) + *(const f2*)(c5 + pp);
        *(f2*)(sel + pp) = s;
    }

    if (dif) {
        // in-place wave-synchronous diff (validated R1/R3): iteration q's reads
        // precede its write; lane63's pos+1 read targets data rewritten only at
        // iteration q+1. pos 2047 reads clamped (own buffer), set to 0.
        for (int q = 0; q < 32; ++q) {
            int pos = q * 64 + lane;
            float a  = sel[pos];
            float an = sel[min(pos + 1, LL - 1)];
            float v  = (pos == (LL - 1)) ? 0.0f : (an - a);
            sel[pos] = v;
        }
    }

    // ---- weights: wave-uniform scalar loads, packed into SGPR pairs ----
    const float* Wg = W + (size_t)((di * 2 + dif) * (KK * GG) + g * KK) * KERNSZ;
    uint64_t wp[KK][4];   // wp[k][m] = (w[k][2m], w[k][2m+1])
    float    w8[KK];      // tap 8 as scalar SGPR (saves 8 pairs)
    #pragma unroll
    for (int k = 0; k < KK; ++k) {
        #pragma unroll
        for (int m = 0; m < 4; ++m) {
            uint32_t lo = __float_as_uint(Wg[k * KERNSZ + 2 * m]);
            uint32_t hi = __float_as_uint(Wg[k * KERNSZ + 2 * m + 1]);
            wp[k][m] = (uint64_t)lo | ((uint64_t)hi << 32);
        }
        w8[k] = Wg[k * KERNSZ + 8];
    }

    f2       accM[KK];
    uint32_t accN[KK];
    #pragma unroll
    for (int k = 0; k < KK; ++k) { accM[k] = f2{0.f, 0.f}; accN[k] = 0u; }

    switch (di) {   // block-uniform branch
        case 0: run_phase2<1>  (sel, lane, Lp, wp, w8, accM, accN); break;
        case 1: run_phase2<2>  (sel, lane, Lp, wp, w8, accM, accN); break;
        case 2: run_phase2<4>  (sel, lane, Lp, wp, w8, accM, accN); break;
        case 3: run_phase2<8>  (sel, lane, Lp, wp, w8, accM, accN); break;
        case 4: run_phase2<16> (sel, lane, Lp, wp, w8, accM, accN); break;
        case 5: run_phase2<32> (sel, lane, Lp, wp, w8, accM, accN); break;
        case 6: run_phase2<64> (sel, lane, Lp, wp, w8, accM, accN); break;
        default: run_phase2<128>(sel, lane, Lp, wp, w8, accM, accN); break;
    }

    // ---- wave butterfly reduction of the 16 accumulators ----
    float* o = out + (size_t)b * 8192 + (size_t)((di * 2 + dif) * 2) * 256 + g * KK;
    #pragma unroll
    for (int k = 0; k < KK; ++k) {
        float a = accM[k].x + accM[k].y;
        unsigned c = accN[k];
        #pragma unroll
        for (int off = 32; off > 0; off >>= 1) {
            a += __shfl_xor(a, off, 64);
            c += __shfl_xor(c, off, 64);
        }
        if (lane == 0) {
            o[k]       = a;          // count_max block (which=0)
            o[256 + k] = (float)c;   // count_min block (which=1)
        }
    }
}

extern "C" void kernel_launch(void* const* d_in, const int* in_sizes, int n_in,
                              void* d_out, int out_size, void* d_ws, size_t ws_size,
                              hipStream_t stream) {
    const float* X = (const float*)d_in[0];
    const float* W = (const float*)d_in[1];
    const int*   I = (const int*)d_in[2];
    float* out = (float*)d_out;

    const int total_waves = BB * NDIL * 2 * GG;       // 32768
    const int blocks = total_waves / WPB;             // 8192
    hydra_kernel<<<blocks, 256, 0, stream>>>(X, W, I, out);
}

// Round 8
// 531.112 us; speedup vs baseline: 2.9052x; 2.9052x over previous
//
#include <hip/hip_runtime.h>
#include <stdint.h>

#define BB     64
#define CC     12
#define LL     2048
#define KERNSZ 9
#define KK     8     // kernels per group
#define GG     32    // groups per branch (_G)
#define NPER   6
#define NDIL   8
#define WPB    4     // waves per block; 4 * 2048 * 4B = 32 KB -> 5 blocks/CU

typedef float f2 __attribute__((ext_vector_type(2)));

// VOP3P packed f32. src1 = wave-uniform SGPR *pair* (w_even, w_odd).
// Broadcast ONE half of src1 to both result halves via op_sel[1]/op_sel_hi[1];
// taps (src0) use natural lo->lo, hi->hi.
__device__ __forceinline__ void pk_fma_wlo(f2& acc, const f2& t, uint64_t wp) {
    asm("v_pk_fma_f32 %0, %1, %2, %0 op_sel:[0,0,0] op_sel_hi:[1,0,1]"
        : "+v"(acc) : "v"(t), "s"(wp));
}
__device__ __forceinline__ void pk_fma_whi(f2& acc, const f2& t, uint64_t wp) {
    asm("v_pk_fma_f32 %0, %1, %2, %0 op_sel:[0,1,0] op_sel_hi:[1,1,1]"
        : "+v"(acc) : "v"(t), "s"(wp));
}
__device__ __forceinline__ f2 pk_mul_wlo(const f2& t, uint64_t wp) {
    f2 d;
    asm("v_pk_mul_f32 %0, %1, %2 op_sel:[0,0] op_sel_hi:[1,0]"
        : "=v"(d) : "v"(t), "s"(wp));
    return d;
}

// Shared conv + max/min + equality-binning on one position pair.
// t[j] = (tap_j @ pos0, tap_j @ pos0+1). kill_hi poisons the .y position.
__device__ __forceinline__ void conv_and_bin(
    const f2 (&t)[KERNSZ], const uint64_t (&wp)[KK][4], const float (&w8)[KK],
    bool kill_hi, f2 (&accM)[KK], uint32_t (&accN)[KK])
{
    const float NANF = __uint_as_float(0x7fc00000u);

    f2 v[KK];   // v[k] = (conv_k@pos0, conv_k@pos0+1)
    #pragma unroll
    for (int k = 0; k < KK; ++k) v[k] = pk_mul_wlo(t[0], wp[k][0]);
    #pragma unroll
    for (int k = 0; k < KK; ++k) pk_fma_whi(v[k], t[1], wp[k][0]);
    #pragma unroll
    for (int m = 1; m < 4; ++m) {
        #pragma unroll
        for (int k = 0; k < KK; ++k) pk_fma_wlo(v[k], t[2 * m], wp[k][m]);
        #pragma unroll
        for (int k = 0; k < KK; ++k) pk_fma_whi(v[k], t[2 * m + 1], wp[k][m]);
    }
    #pragma unroll
    for (int k = 0; k < KK; ++k) {
        v[k].x = fmaf(w8[k], t[8].x, v[k].x);
        v[k].y = fmaf(w8[k], t[8].y, v[k].y);
    }

    float mxa = fmaxf(fmaxf(v[0].x, v[1].x), fmaxf(v[2].x, v[3].x));
    float mxb = fmaxf(fmaxf(v[4].x, v[5].x), fmaxf(v[6].x, v[7].x));
    float mx  = fmaxf(mxa, mxb);
    float mya = fmaxf(fmaxf(v[0].y, v[1].y), fmaxf(v[2].y, v[3].y));
    float myb = fmaxf(fmaxf(v[4].y, v[5].y), fmaxf(v[6].y, v[7].y));
    float my  = fmaxf(mya, myb);
    float nxa = fminf(fminf(v[0].x, v[1].x), fminf(v[2].x, v[3].x));
    float nxb = fminf(fminf(v[4].x, v[5].x), fminf(v[6].x, v[7].x));
    float nx  = fminf(nxa, nxb);
    float nya = fminf(fminf(v[0].y, v[1].y), fminf(v[2].y, v[3].y));
    float nyb = fminf(fminf(v[4].y, v[5].y), fminf(v[6].y, v[7].y));
    float ny  = fminf(nya, nyb);

    if (kill_hi) { my = NANF; ny = NANF; }   // NaN never compares equal

    #pragma unroll
    for (int k = 0; k < KK; ++k) {
        f2 am;
        am.x = (v[k].x == mx) ? v[k].x : 0.0f;   // exact: mx bit-equals winner
        am.y = (v[k].y == my) ? v[k].y : 0.0f;
        accM[k] += am;                            // v_pk_add_f32
        accN[k] += (v[k].x == nx) ? 1u : 0u;
        accN[k] += (v[k].y == ny) ? 1u : 0u;
    }
}

// Edge iteration: clamped + masked tap loads (replaces LDS pads).
__device__ __forceinline__ void edge_iter(
    const float* __restrict__ sel, int pos0, int D, unsigned Lp,
    const uint64_t (&wp)[KK][4], const float (&w8)[KK],
    f2 (&accM)[KK], uint32_t (&accN)[KK])
{
    f2 t[KERNSZ];
    #pragma unroll
    for (int j = 0; j < KERNSZ; ++j) {
        int ix = pos0 + (j - 4) * D;
        int iy = ix + 1;
        float tx = sel[min(max(ix, 0), LL - 1)];   // stay inside own buffer
        float ty = sel[min(max(iy, 0), LL - 1)];
        t[j].x = ((unsigned)ix < Lp) ? tx : 0.0f;  // zero-pad semantics
        t[j].y = ((unsigned)iy < Lp) ? ty : 0.0f;
    }
    conv_and_bin(t, wp, w8, (unsigned)(pos0 + 1) >= Lp, accM, accN);
}

// Interior: all taps provably in [0, Lp) -> unchecked LDS pair loads.
template <int D>
__device__ __forceinline__ void run_phase2(
    const float* __restrict__ sel, int lane, unsigned Lp,
    const uint64_t (&wp)[KK][4], const float (&w8)[KK],
    f2 (&accM)[KK], uint32_t (&accN)[KK])
{
    // pair-iteration q covers positions [q*128, q*128+127]
    // interior iff q*128 - 4D >= 0 and q*128 + 127 + 1 + 4D <= 2047
    constexpr int QLO = (4 * D + 127) / 128;
    constexpr int QHI = (1919 - 4 * D) / 128;

    #pragma unroll 2
    for (int q = QLO; q <= QHI; ++q) {
        const int pos0 = q * 128 + 2 * lane;
        const float* pb = sel + pos0 - 4 * D;   // 8B-aligned (all terms even)

        f2 t[KERNSZ];
        #pragma unroll
        for (int j = 0; j < KERNSZ; ++j) {
            if constexpr (D % 2 == 0) {
                t[j] = *(const f2*)(pb + j * D);   // ds_read_b64, imm offset
            } else {
                t[j].x = pb[j * D];                // ds_read2_b32
                t[j].y = pb[j * D + 1];
            }
        }
        conv_and_bin(t, wp, w8, false, accM, accN);
    }

    // edge iterations (few; D=128 worst at 9/16)
    #pragma unroll 1
    for (int q = 0; q < QLO; ++q)
        edge_iter(sel, q * 128 + 2 * lane, D, Lp, wp, w8, accM, accN);
    #pragma unroll 1
    for (int q = QHI + 1; q < 16; ++q)
        edge_iter(sel, q * 128 + 2 * lane, D, Lp, wp, w8, accM, accN);
}

// NOTE: no min-waves arg — __launch_bounds__(256,5) in R7 capped the allocator
// at 48 VGPR and produced 2.9 GB of scratch spill (dur 1543 us). LDS size is
// the occupancy knob here: 32 KB/block -> 5 blocks/CU if VGPR <= ~102.
__global__ __launch_bounds__(256) void hydra_kernel(
    const float* __restrict__ X,    // [B, C, L]
    const float* __restrict__ W,    // [NDIL, 2, KK*GG, 1, KERNSZ]
    const int*   __restrict__ I,    // [NDIL, 2, GG, NPER]
    float*       __restrict__ out)  // [B, 8192]
{
    __shared__ float lds[WPB][LL];   // exactly 32 KB/block

    const int tid  = threadIdx.x;
    const int wave = tid >> 6;
    const int lane = tid & 63;
    const int wid  = blockIdx.x * WPB + wave;   // 0..32767
    // task decode: wid = b*512 + di*64 + dif*32 + g
    const int b   = wid >> 9;
    const int r   = wid & 511;
    const int di  = r >> 6;
    const int r2  = r & 63;
    const int dif = r2 >> 5;
    const int g   = r2 & 31;
    const unsigned Lp = LL - dif;    // 2048 or 2047

    float* sel = lds[wave];

    // ---- phase 1: channel-subset sum S into sel[0..2047] (f2 loads) ----
    const int* Ig = I + ((size_t)((di * 2 + dif) * GG + g)) * NPER;
    const float* xb = X + (size_t)b * CC * LL;
    const float* c0 = xb + Ig[0] * LL;
    const float* c1 = xb + Ig[1] * LL;
    const float* c2 = xb + Ig[2] * LL;
    const float* c3 = xb + Ig[3] * LL;
    const float* c4 = xb + Ig[4] * LL;
    const float* c5 = xb + Ig[5] * LL;

    #pragma unroll 1
    for (int q = 0; q < 16; ++q) {
        int pp = (q * 64 + lane) * 2;
        f2 s = *(const f2*)(c0 + pp) + *(const f2*)(c1 + pp)
             + *(const f2*)(c2 + pp) + *(const f2*)(c3 + pp)
             + *(const f2*)(c4 + pp) + *(const f2*)(c5 + pp);
        *(f2*)(sel + pp) = s;
    }

    if (dif) {
        // in-place wave-synchronous diff (validated R1/R3): iteration q's reads
        // precede its write; lane63's pos+1 read targets data rewritten only at
        // iteration q+1. pos 2047 reads clamped (own buffer), set to 0.
        for (int q = 0; q < 32; ++q) {
            int pos = q * 64 + lane;
            float a  = sel[pos];
            float an = sel[min(pos + 1, LL - 1)];
            float v  = (pos == (LL - 1)) ? 0.0f : (an - a);
            sel[pos] = v;
        }
    }

    // ---- weights: wave-uniform scalar loads, packed into SGPR pairs ----
    const float* Wg = W + (size_t)((di * 2 + dif) * (KK * GG) + g * KK) * KERNSZ;
    uint64_t wp[KK][4];   // wp[k][m] = (w[k][2m], w[k][2m+1])
    float    w8[KK];      // tap 8 as scalar SGPR (saves 8 pairs)
    #pragma unroll
    for (int k = 0; k < KK; ++k) {
        #pragma unroll
        for (int m = 0; m < 4; ++m) {
            uint32_t lo = __float_as_uint(Wg[k * KERNSZ + 2 * m]);
            uint32_t hi = __float_as_uint(Wg[k * KERNSZ + 2 * m + 1]);
            wp[k][m] = (uint64_t)lo | ((uint64_t)hi << 32);
        }
        w8[k] = Wg[k * KERNSZ + 8];
    }

    f2       accM[KK];
    uint32_t accN[KK];
    #pragma unroll
    for (int k = 0; k < KK; ++k) { accM[k] = f2{0.f, 0.f}; accN[k] = 0u; }

    switch (di) {   // block-uniform branch
        case 0: run_phase2<1>  (sel, lane, Lp, wp, w8, accM, accN); break;
        case 1: run_phase2<2>  (sel, lane, Lp, wp, w8, accM, accN); break;
        case 2: run_phase2<4>  (sel, lane, Lp, wp, w8, accM, accN); break;
        case 3: run_phase2<8>  (sel, lane, Lp, wp, w8, accM, accN); break;
        case 4: run_phase2<16> (sel, lane, Lp, wp, w8, accM, accN); break;
        case 5: run_phase2<32> (sel, lane, Lp, wp, w8, accM, accN); break;
        case 6: run_phase2<64> (sel, lane, Lp, wp, w8, accM, accN); break;
        default: run_phase2<128>(sel, lane, Lp, wp, w8, accM, accN); break;
    }

    // ---- wave butterfly reduction of the 16 accumulators ----
    float* o = out + (size_t)b * 8192 + (size_t)((di * 2 + dif) * 2) * 256 + g * KK;
    #pragma unroll
    for (int k = 0; k < KK; ++k) {
        float a = accM[k].x + accM[k].y;
        unsigned c = accN[k];
        #pragma unroll
        for (int off = 32; off > 0; off >>= 1) {
            a += __shfl_xor(a, off, 64);
            c += __shfl_xor(c, off, 64);
        }
        if (lane == 0) {
            o[k]       = a;          // count_max block (which=0)
            o[256 + k] = (float)c;   // count_min block (which=1)
        }
    }
}

extern "C" void kernel_launch(void* const* d_in, const int* in_sizes, int n_in,
                              void* d_out, int out_size, void* d_ws, size_t ws_size,
                              hipStream_t stream) {
    const float* X = (const float*)d_in[0];
    const float* W = (const float*)d_in[1];
    const int*   I = (const int*)d_in[2];
    float* out = (float*)d_out;

    const int total_waves = BB * NDIL * 2 * GG;       // 32768
    const int blocks = total_waves / WPB;             // 8192
    hydra_kernel<<<blocks, 256, 0, stream>>>(X, W, I, out);
}

// Round 9
// 275.732 us; speedup vs baseline: 5.5959x; 1.9262x over previous
//
#include <hip/hip_runtime.h>
#include <stdint.h>

#define BB     64
#define CC     12
#define LL     2048
#define KERNSZ 9
#define KK     8     // kernels per group
#define GG     32    // groups per branch (_G)
#define NPER   6
#define NDIL   8
#define PAD    256   // covers D<=64 fully; D=128 edges handled by clamp
#define MAIN   2048
#define BUFSZ  (PAD + MAIN + PAD)   // 2560 floats = 10 KB per wave
#define WPB    4     // 4 * 10 KB = 40 KB/block -> 4 blocks/CU (160 KB exactly)

typedef float f2 __attribute__((ext_vector_type(2)));

// R4-proven VOP3P forms: src1 = wave-uniform SGPR pair (w[2c][j], w[2c+1][j]);
// src0 tap broadcast from the LOW half via op_sel_hi[0]=0.
__device__ __forceinline__ void pk_fma_bcast(f2& acc, const f2& t, uint64_t wpair) {
    asm("v_pk_fma_f32 %0, %1, %2, %0 op_sel:[0,0,0] op_sel_hi:[0,1,1]"
        : "+v"(acc) : "v"(t), "s"(wpair));
}
__device__ __forceinline__ f2 pk_mul_bcast(const f2& t, uint64_t wpair) {
    f2 d;
    asm("v_pk_mul_f32 %0, %1, %2 op_sel:[0,0] op_sel_hi:[0,1]"
        : "=v"(d) : "v"(t), "s"(wpair));
    return d;
}

// Conv + max/min + equality binning for ONE position (R4 body, factored).
// t[j].x holds tap j. kill poisons the position (diff branch pos 2047).
__device__ __forceinline__ void conv_bin(
    const f2 (&t)[KERNSZ], const uint64_t (&wp)[4][KERNSZ],
    bool kill, f2 (&accM)[4], uint32_t (&accN)[KK])
{
    const float NANF = __uint_as_float(0x7fc00000u);

    f2 v2[4];                              // (v0,v1)(v2,v3)(v4,v5)(v6,v7)
    #pragma unroll
    for (int c = 0; c < 4; ++c)
        v2[c] = pk_mul_bcast(t[0], wp[c][0]);
    #pragma unroll
    for (int j = 1; j < KERNSZ; ++j)
        #pragma unroll
        for (int c = 0; c < 4; ++c)
            pk_fma_bcast(v2[c], t[j], wp[c][j]);

    // balanced max/min trees on the (separately addressable) pair halves
    float ma = fmaxf(fmaxf(v2[0].x, v2[0].y), fmaxf(v2[1].x, v2[1].y));
    float mb = fmaxf(fmaxf(v2[2].x, v2[2].y), fmaxf(v2[3].x, v2[3].y));
    float mv = fmaxf(ma, mb);
    float na = fminf(fminf(v2[0].x, v2[0].y), fminf(v2[1].x, v2[1].y));
    float nb = fminf(fminf(v2[2].x, v2[2].y), fminf(v2[3].x, v2[3].y));
    float nv = fminf(na, nb);

    if (kill) { mv = NANF; nv = NANF; }    // NaN never compares equal

    #pragma unroll
    for (int c = 0; c < 4; ++c) {
        f2 am;
        am.x = (v2[c].x == mv) ? v2[c].x : 0.0f;   // exact: mv bit-equals winner
        am.y = (v2[c].y == mv) ? v2[c].y : 0.0f;
        accM[c] += am;                              // v_pk_add_f32
        accN[2 * c]     += (v2[c].x == nv) ? 1u : 0u;
        accN[2 * c + 1] += (v2[c].y == nv) ? 1u : 0u;
    }
}

// Phase 2, specialized on compile-time dilation D (tap offsets immediate).
template <int D>
__device__ __forceinline__ void run_phase2(
    const float* __restrict__ sel, int lane, int dif,
    const uint64_t (&wp)[4][KERNSZ], f2 (&accM)[4], uint32_t (&accN)[KK])
{
    // interior iff pos-4D >= -PAD and pos+4D <= 2047+PAD
    constexpr int EXT = 4 * D - PAD;
    constexpr int QLO = (EXT > 0) ? (EXT + 63) / 64 : 0;          // D=128 -> 4
    constexpr int QHI = (EXT > 0) ? (2047 + PAD - 4 * D - 63) / 64 : 31;  // -> 27

    for (int q = QLO; q <= QHI; ++q) {
        const int pos = q * 64 + lane;
        const float* p = sel + pos - 4 * D;

        f2 t[KERNSZ];
        #pragma unroll
        for (int j = 0; j < KERNSZ; ++j)
            t[j].x = p[j * D];             // imm offsets; pads make all valid

        conv_bin(t, wp, dif && q == 31 && lane == 63, accM, accN);
    }

    if constexpr (EXT > 0) {
        // edge iterations (D=128 only): clamp into the zeroed pads -> any
        // out-of-range tap reads 0, matching zero-pad semantics.
        #pragma unroll 1
        for (int q = 0; q < QLO; ++q) {
            const int pos = q * 64 + lane;
            f2 t[KERNSZ];
            #pragma unroll
            for (int j = 0; j < KERNSZ; ++j) {
                int idx = pos + (j - 4) * D;
                t[j].x = sel[max(idx, -PAD)];          // right side in-bounds here
            }
            conv_bin(t, wp, false, accM, accN);
        }
        #pragma unroll 1
        for (int q = QHI + 1; q < 32; ++q) {
            const int pos = q * 64 + lane;
            f2 t[KERNSZ];
            #pragma unroll
            for (int j = 0; j < KERNSZ; ++j) {
                int idx = pos + (j - 4) * D;
                t[j].x = sel[min(idx, MAIN - 1 + PAD)]; // left side in-bounds here
            }
            conv_bin(t, wp, dif && q == 31 && lane == 63, accM, accN);
        }
    }
}

// NOTE: no min-waves arg (R7: __launch_bounds__(256,5) -> 48 VGPR -> 2.9 GB
// spill). Occupancy knob is LDS: 40 KB/block -> 4 blocks/CU if VGPR <= 128.
__global__ __launch_bounds__(256) void hydra_kernel(
    const float* __restrict__ X,    // [B, C, L]
    const float* __restrict__ W,    // [NDIL, 2, KK*GG, 1, KERNSZ]
    const int*   __restrict__ I,    // [NDIL, 2, GG, NPER]
    float*       __restrict__ out)  // [B, 8192]
{
    __shared__ float lds[WPB][BUFSZ];   // 40960 B/block

    const int tid  = threadIdx.x;
    const int wave = tid >> 6;
    const int lane = tid & 63;
    const int wid  = blockIdx.x * WPB + wave;   // 0..32767
    // task decode: wid = b*512 + di*64 + dif*32 + g
    const int b   = wid >> 9;
    const int r   = wid & 511;
    const int di  = r >> 6;
    const int r2  = r & 63;
    const int dif = r2 >> 5;
    const int g   = r2 & 31;

    float* buf = lds[wave];
    float* sel = buf + PAD;

    // ---- zero halo pads ----
    #pragma unroll
    for (int i = 0; i < PAD; i += 128) {
        *(f2*)(buf + i + 2 * lane)              = f2{0.f, 0.f};
        *(f2*)(buf + PAD + MAIN + i + 2 * lane) = f2{0.f, 0.f};
    }

    // ---- phase 1: channel-subset sum S into sel[0..2047] (f2 loads) ----
    const int* Ig = I + ((size_t)((di * 2 + dif) * GG + g)) * NPER;
    const float* xb = X + (size_t)b * CC * LL;
    const float* c0 = xb + Ig[0] * LL;
    const float* c1 = xb + Ig[1] * LL;
    const float* c2 = xb + Ig[2] * LL;
    const float* c3 = xb + Ig[3] * LL;
    const float* c4 = xb + Ig[4] * LL;
    const float* c5 = xb + Ig[5] * LL;

    #pragma unroll 1
    for (int q = 0; q < 16; ++q) {
        int pp = (q * 64 + lane) * 2;
        f2 s = *(const f2*)(c0 + pp) + *(const f2*)(c1 + pp)
             + *(const f2*)(c2 + pp) + *(const f2*)(c3 + pp)
             + *(const f2*)(c4 + pp) + *(const f2*)(c5 + pp);
        *(f2*)(sel + pp) = s;
    }

    if (dif) {
        // in-place wave-synchronous diff (validated R1/R3/R4): iteration q's
        // reads precede its write; lane63's pos+1 read targets data rewritten
        // only at iteration q+1. sel[2048] is the zeroed right pad.
        for (int q = 0; q < 32; ++q) {
            int pos = q * 64 + lane;
            float a  = sel[pos];
            float an = sel[pos + 1];
            float v  = (pos == (LL - 1)) ? 0.0f : (an - a);
            sel[pos] = v;   // sel[2047] := 0 keeps zero-pad semantics
        }
    }

    // ---- weights: wave-uniform scalar loads, packed into SGPR pairs ----
    const float* Wg = W + (size_t)((di * 2 + dif) * (KK * GG) + g * KK) * KERNSZ;
    uint64_t wp[4][KERNSZ];   // wp[c][j] = (w[2c][j], w[2c+1][j])
    #pragma unroll
    for (int c = 0; c < 4; ++c)
        #pragma unroll
        for (int j = 0; j < KERNSZ; ++j) {
            uint32_t lo = __float_as_uint(Wg[(2 * c)     * KERNSZ + j]);
            uint32_t hi = __float_as_uint(Wg[(2 * c + 1) * KERNSZ + j]);
            wp[c][j] = (uint64_t)lo | ((uint64_t)hi << 32);
        }

    f2       accM[4];
    uint32_t accN[KK];
    #pragma unroll
    for (int c = 0; c < 4; ++c) accM[c] = f2{0.f, 0.f};
    #pragma unroll
    for (int k = 0; k < KK; ++k) accN[k] = 0u;

    switch (di) {   // block-uniform branch
        case 0: run_phase2<1>  (sel, lane, dif, wp, accM, accN); break;
        case 1: run_phase2<2>  (sel, lane, dif, wp, accM, accN); break;
        case 2: run_phase2<4>  (sel, lane, dif, wp, accM, accN); break;
        case 3: run_phase2<8>  (sel, lane, dif, wp, accM, accN); break;
        case 4: run_phase2<16> (sel, lane, dif, wp, accM, accN); break;
        case 5: run_phase2<32> (sel, lane, dif, wp, accM, accN); break;
        case 6: run_phase2<64> (sel, lane, dif, wp, accM, accN); break;
        default: run_phase2<128>(sel, lane, dif, wp, accM, accN); break;
    }

    // ---- wave butterfly reduction of the 16 accumulators ----
    float* o = out + (size_t)b * 8192 + (size_t)((di * 2 + dif) * 2) * 256 + g * KK;
    #pragma unroll
    for (int k = 0; k < KK; ++k) {
        float a = (k & 1) ? accM[k >> 1].y : accM[k >> 1].x;
        unsigned c = accN[k];
        #pragma unroll
        for (int off = 32; off > 0; off >>= 1) {
            a += __shfl_xor(a, off, 64);
            c += __shfl_xor(c, off, 64);
        }
        if (lane == 0) {
            o[k]       = a;          // count_max block (which=0)
            o[256 + k] = (float)c;   // count_min block (which=1)
        }
    }
}

extern "C" void kernel_launch(void* const* d_in, const int* in_sizes, int n_in,
                              void* d_out, int out_size, void* d_ws, size_t ws_size,
                              hipStream_t stream) {
    const float* X = (const float*)d_in[0];
    const float* W = (const float*)d_in[1];
    const int*   I = (const int*)d_in[2];
    float* out = (float*)d_out;

    const int total_waves = BB * NDIL * 2 * GG;       // 32768
    const int blocks = total_waves / WPB;             // 8192
    hydra_kernel<<<blocks, 256, 0, stream>>>(X, W, I, out);
}